// Round 13
// baseline (317.926 us; speedup 1.0000x reference)
//
#include <hip/hip_runtime.h>
#include <hip/hip_cooperative_groups.h>

// QueryAndGroup — test dims B=2, Nb=512, N=1024, M=64, K=216, C=32, ns=32.
// Inputs f32; OUTPUT f32: [group_features (L,3+C) | set_new_indices (L,)].
// Round-12 post-mortem: neutral vs round 11 (109.6 vs 110.3) — timed window is
// dominated by harness poison fills (41 us, 256 MB -> also flushes L2 every
// iter) + ~22 restore dispatches + my 4 dispatch gaps. Round-13: ONE
// cooperative launch (count -> grid.sync -> scan -> grid.sync -> emit), output
// zeroing folded in, count loop batched x4 against cold-miss latency, matched
// j's recorded in ws so emit is a warm, fully-coalesced writer. Fallback to
// the proven 3-kernel path if hipLaunchCooperativeKernel errors.

#pragma clang fp contract(off)

namespace cg = cooperative_groups;

typedef unsigned long long u64;

#define MAXN 4096

// ======================= cooperative all-in-one kernel =======================
__global__ __launch_bounds__(256) void coop_kernel(
    const float* __restrict__ xyz, const float* __restrict__ new_xyz,
    const float* __restrict__ rois, const float* __restrict__ features,
    int* __restrict__ counts, int* __restrict__ offsets, int* __restrict__ ballidx,
    float* __restrict__ out_feat, float* __restrict__ out_idx,
    int N, int Nb, int M, int K, int C, int nsample, int totalOut)
{
    cg::grid_group grid = cg::this_grid();

    __shared__ int plist[4][64];
    __shared__ int scanAux[4];

    const int wave = threadIdx.x >> 6;
    const int lane = threadIdx.x & 63;
    const int r = blockIdx.x * 4 + wave;
    const u64 laneLt = (1ull << lane) - 1ull;
    const int gtid = blockIdx.x * 256 + threadIdx.x;
    const int gthreads = gridDim.x * 256;

    // ---- Phase 0: zero the output (replaces hipMemsetAsync dispatch) ----
    for (int i = gtid; i < totalOut; i += gthreads) out_feat[i] = 0.0f;

    // ---- Phase A: count + record matched j's (wave per row) ----
    if (r < N) {
        const int b  = r / Nb;
        const float px = xyz[3 * r + 0];
        const float py = xyz[3 * r + 1];
        const float pz = xyz[3 * r + 2];

        bool pass = false;
        if (lane < M) {
            const float* rp = rois + (size_t)(b * M + lane) * 7;
            const float dx = rp[3], dy = rp[4], dz = rp[5];
            const float r2 = (dx * dx + dy * dy) + dz * dz;   // numpy assoc
            const float ex = px - rp[0], ey = py - rp[1], ez = pz - rp[2];
            pass = ((ex * ex + ey * ey) + ez * ez) <= r2;
        }
        const u64 roiMask = __ballot(pass);
        if (roiMask) {
            if (pass) plist[wave][__popcll(roiMask & laneLt)] = lane;  // asc m
            const int P = __popcll(roiMask);
            const int total = P * K;
            const float* nb_ = new_xyz + (size_t)(b * M * K) * 3;
            int* bi = ballidx + (size_t)r * nsample;

            int cnt = 0;
            for (int base = 0; base < total && cnt < nsample; base += 256) {
                bool match[4];
                int jj[4];
                // issue all loads for 4 sub-iterations before any ballot
                #pragma unroll
                for (int u = 0; u < 4; u++) {
                    const int p = base + u * 64 + lane;
                    match[u] = false; jj[u] = 0;
                    if (p < total) {
                        const int ri = p / K;
                        const int k  = p - ri * K;
                        const int j  = plist[wave][ri] * K + k;
                        jj[u] = j;
                        const float* gp = nb_ + (size_t)j * 3;
                        const float ax = px - gp[0], ay = py - gp[1], az = pz - gp[2];
                        match[u] = ((ax * ax + ay * ay) + az * az) <= 1.0f;
                    }
                }
                #pragma unroll
                for (int u = 0; u < 4; u++) {
                    const u64 mm = __ballot(match[u]);
                    const int slot = cnt + __popcll(mm & laneLt);
                    if (match[u] && slot < nsample) bi[slot] = jj[u];
                    cnt += __popcll(mm);
                }
            }
            if (lane == 0) counts[r] = cnt > nsample ? nsample : cnt;
        } else {
            if (lane == 0) counts[r] = 0;
        }
    }

    grid.sync();

    // ---- Phase B: exclusive scan of counts[N] by block 0 ----
    if (blockIdx.x == 0) {
        const int G = (N + 255) / 256;           // elems per thread
        const int start = threadIdx.x * G;
        int s = 0;
        for (int i = 0; i < G; i++)
            if (start + i < N) s += counts[start + i];
        int incl = s;
        #pragma unroll
        for (int d = 1; d < 64; d <<= 1) {
            int v = __shfl_up(incl, d, 64);
            if (lane >= d) incl += v;
        }
        if (lane == 63) scanAux[wave] = incl;
        __syncthreads();
        if (threadIdx.x == 0) {
            int acc = 0;
            #pragma unroll
            for (int w = 0; w < 4; w++) { int t = scanAux[w]; scanAux[w] = acc; acc += t; }
        }
        __syncthreads();
        int run = scanAux[wave] + incl - s;
        for (int i = 0; i < G; i++) {
            if (start + i < N) { offsets[start + i] = run; run += counts[start + i]; }
        }
    }

    grid.sync();

    // ---- Phase C: emit (wave per row; warm L2; contiguous coalesced writes) -
    if (r < N) {
        const int cnt = counts[r];
        if (cnt > 0) {
            const int b  = r / Nb;
            const int MK = M * K;
            const int obase = offsets[r];
            const int* bi = ballidx + (size_t)r * nsample;
            const float px = xyz[3 * r + 0];
            const float py = xyz[3 * r + 1];
            const float pz = xyz[3 * r + 2];
            const float* fr = features + (size_t)r * C;
            const float* nb_ = new_xyz + (size_t)b * MK * 3;
            const int W = 3 + C;

            // feature block: cnt*W contiguous floats starting at obase*W
            float* dst = out_feat + (size_t)obase * W;
            const int tot = cnt * W;
            for (int idx = lane; idx < tot; idx += 64) {
                const int s = idx / W;
                const int c = idx - s * W;
                const int j = bi[s];
                float v;
                if (c == 0)      v = px - nb_[(size_t)j * 3 + 0];
                else if (c == 1) v = py - nb_[(size_t)j * 3 + 1];
                else if (c == 2) v = pz - nb_[(size_t)j * 3 + 2];
                else             v = fr[c - 3];
                dst[idx] = v;
            }
            for (int s = lane; s < cnt; s += 64)
                out_idx[obase + s] = (float)(b * MK + bi[s]);
        }
    }
}

// ======================= fallback: proven 3-kernel path ======================
__global__ __launch_bounds__(256) void count_kernel(
    const float* __restrict__ xyz, const float* __restrict__ new_xyz,
    const float* __restrict__ rois, int* __restrict__ counts,
    int N, int Nb, int M, int K, int nsample)
{
    __shared__ int plist[4][64];
    const int wave = threadIdx.x >> 6;
    const int lane = threadIdx.x & 63;
    const int r = blockIdx.x * 4 + wave;
    if (r >= N) return;
    const int b  = r / Nb;
    const float px = xyz[3 * r + 0], py = xyz[3 * r + 1], pz = xyz[3 * r + 2];
    bool pass = false;
    if (lane < M) {
        const float* rp = rois + (size_t)(b * M + lane) * 7;
        const float dx = rp[3], dy = rp[4], dz = rp[5];
        const float r2 = (dx * dx + dy * dy) + dz * dz;
        const float ex = px - rp[0], ey = py - rp[1], ez = pz - rp[2];
        pass = ((ex * ex + ey * ey) + ez * ez) <= r2;
    }
    const u64 roiMask = __ballot(pass);
    if (!roiMask) { if (lane == 0) counts[r] = 0; return; }
    const u64 laneLt = (1ull << lane) - 1ull;
    if (pass) plist[wave][__popcll(roiMask & laneLt)] = lane;
    const int P = __popcll(roiMask);
    const int total = P * K;
    const float* nb_ = new_xyz + (size_t)(b * M * K) * 3;
    int cnt = 0;
    for (int base = 0; base < total && cnt < nsample; base += 64) {
        const int p = base + lane;
        bool match = false;
        if (p < total) {
            const int ri = p / K;
            const int k  = p - ri * K;
            const float* gp = nb_ + (size_t)(plist[wave][ri] * K + k) * 3;
            const float ax = px - gp[0], ay = py - gp[1], az = pz - gp[2];
            match = ((ax * ax + ay * ay) + az * az) <= 1.0f;
        }
        cnt += __popcll(__ballot(match));
    }
    if (lane == 0) counts[r] = cnt > nsample ? nsample : cnt;
}

__global__ __launch_bounds__(1024) void scan_kernel(
    const int* __restrict__ counts, int* __restrict__ offsets, int N)
{
    __shared__ int waveAux[16];
    const int t = threadIdx.x;
    const int lane = t & 63;
    const int wid = t >> 6;
    const int base = t * 4;
    int c[4];
    int s = 0;
    #pragma unroll
    for (int i = 0; i < 4; i++) {
        c[i] = (base + i < N) ? counts[base + i] : 0;
        s += c[i];
    }
    int incl = s;
    #pragma unroll
    for (int d = 1; d < 64; d <<= 1) {
        int v = __shfl_up(incl, d, 64);
        if (lane >= d) incl += v;
    }
    if (lane == 63) waveAux[wid] = incl;
    __syncthreads();
    if (t < 16) {
        int v = waveAux[t];
        #pragma unroll
        for (int d = 1; d < 16; d <<= 1) {
            int u = __shfl_up(v, d, 64);
            if (t >= d) v += u;
        }
        waveAux[t] = v;
    }
    __syncthreads();
    int run = (wid ? waveAux[wid - 1] : 0) + incl - s;
    #pragma unroll
    for (int i = 0; i < 4; i++) {
        if (base + i < N) offsets[base + i] = run;
        run += c[i];
    }
}

__global__ __launch_bounds__(256) void emit_kernel(
    const float* __restrict__ xyz, const float* __restrict__ new_xyz,
    const float* __restrict__ rois, const float* __restrict__ features,
    const int* __restrict__ offsets,
    float* __restrict__ out_feat, float* __restrict__ out_idx,
    int N, int Nb, int M, int K, int C, int nsample)
{
    __shared__ int plist[4][64];
    const int wave = threadIdx.x >> 6;
    const int lane = threadIdx.x & 63;
    const int r = blockIdx.x * 4 + wave;
    if (r >= N) return;
    const int b  = r / Nb;
    const int MK = M * K;
    const float px = xyz[3 * r + 0], py = xyz[3 * r + 1], pz = xyz[3 * r + 2];
    bool pass = false;
    if (lane < M) {
        const float* rp = rois + (size_t)(b * M + lane) * 7;
        const float dx = rp[3], dy = rp[4], dz = rp[5];
        const float r2 = (dx * dx + dy * dy) + dz * dz;
        const float ex = px - rp[0], ey = py - rp[1], ez = pz - rp[2];
        pass = ((ex * ex + ey * ey) + ez * ez) <= r2;
    }
    const u64 roiMask = __ballot(pass);
    if (!roiMask) return;
    const u64 laneLt = (1ull << lane) - 1ull;
    if (pass) plist[wave][__popcll(roiMask & laneLt)] = lane;
    const int P = __popcll(roiMask);
    const int total = P * K;
    const float* nb_ = new_xyz + (size_t)b * MK * 3;
    const int obase = offsets[r];
    const float* fr = features + (size_t)r * C;
    int cnt = 0;
    for (int base = 0; base < total && cnt < nsample; base += 64) {
        const int p = base + lane;
        bool match = false;
        float ax = 0.f, ay = 0.f, az = 0.f;
        int j = 0;
        if (p < total) {
            const int ri = p / K;
            const int k  = p - ri * K;
            j = plist[wave][ri] * K + k;
            const float* gp = nb_ + (size_t)j * 3;
            ax = px - gp[0]; ay = py - gp[1]; az = pz - gp[2];
            match = ((ax * ax + ay * ay) + az * az) <= 1.0f;
        }
        const u64 mm = __ballot(match);
        const int slot = cnt + __popcll(mm & laneLt);
        if (match && slot < nsample) {
            const int o = obase + slot;
            float* of = out_feat + (size_t)o * (3 + C);
            of[0] = ax; of[1] = ay; of[2] = az;
            for (int i = 0; i < C; i++) of[3 + i] = fr[i];
            out_idx[o] = (float)(b * MK + j);
        }
        cnt += __popcll(mm);
    }
}

extern "C" void kernel_launch(void* const* d_in, const int* in_sizes, int n_in,
                              void* d_out, int out_size, void* d_ws, size_t ws_size,
                              hipStream_t stream) {
    if (n_in < 5) return;

    // ---- Role assignment by SIZE (unique on the true test sizes). ----
    int bc = 0;
    for (int i = 1; i < n_in; i++) if (in_sizes[i] < in_sizes[bc]) bc = i;
    const int B = in_sizes[bc];
    if (B < 1) return;

    int xi = -1, nwi = -1, ri = -1, fi = -1;
    int N = 0, M = 0, K = 0, C = 0, nsample = 0;

    for (int rr = 0; rr < n_in && xi < 0; rr++) {
        if (rr == bc) continue;
        if (in_sizes[rr] % (7 * B)) continue;            // rois = B*M*7
        const int M_ = in_sizes[rr] / (7 * B);
        if (M_ < 1 || M_ > 64) continue;
        for (int xx = 0; xx < n_in && xi < 0; xx++) {
            if (xx == bc || xx == rr) continue;
            if (in_sizes[xx] % 3) continue;              // xyz = N*3
            const int N_ = in_sizes[xx] / 3;
            if (N_ < B || N_ % B || N_ > MAXN) continue;
            for (int nn = 0; nn < n_in && xi < 0; nn++) {
                if (nn == bc || nn == rr || nn == xx) continue;
                if (in_sizes[nn] % (3 * B * M_)) continue;   // new_xyz = B*M*K*3
                const int K_ = in_sizes[nn] / (3 * B * M_);
                if (K_ < 1) continue;
                for (int ff = 0; ff < n_in && xi < 0; ff++) {
                    if (ff == bc || ff == rr || ff == xx || ff == nn) continue;
                    if (in_sizes[ff] % N_) continue;         // features = N*C
                    const int C_ = in_sizes[ff] / N_;
                    if (C_ < 1) continue;
                    if (out_size % (4 + C_)) continue;       // out = L*(4+C) f32
                    const long long L_ = (long long)out_size / (4 + C_);
                    if (L_ % N_) continue;
                    const int ns = (int)(L_ / N_);
                    if (ns < 1 || ns > 1024) continue;
                    xi = xx; nwi = nn; ri = rr; fi = ff;
                    N = N_; M = M_; K = K_; C = C_; nsample = ns;
                }
            }
        }
    }
    if (xi < 0) return;

    const float* xyz      = (const float*)d_in[xi];
    const float* new_xyz  = (const float*)d_in[nwi];
    const float* rois     = (const float*)d_in[ri];
    const float* features = (const float*)d_in[fi];
    const int Nb = N / B;

    const size_t L      = (size_t)N * nsample;
    const size_t chunk0 = L * (size_t)(3 + C);
    const int totalOut  = (int)(chunk0 + L);

    float* out_feat = (float*)d_out;
    float* out_idx  = out_feat + chunk0;

    // ws: counts[N] + offsets[N] + ballidx[N*ns]
    const size_t wsNeed = ((size_t)2 * N + (size_t)N * nsample) * sizeof(int);
    if (ws_size < wsNeed) return;
    int* counts  = (int*)d_ws;
    int* offsets = counts + N;
    int* ballidx = offsets + N;

    const int blocks = (N + 3) / 4;   // one wave per row

    // ---- Preferred: single cooperative launch (no memset dispatch) ----
    void* args[] = {
        (void*)&xyz, (void*)&new_xyz, (void*)&rois, (void*)&features,
        (void*)&counts, (void*)&offsets, (void*)&ballidx,
        (void*)&out_feat, (void*)&out_idx,
        (void*)&N, (void*)&Nb, (void*)&M, (void*)&K, (void*)&C,
        (void*)&nsample, (void*)&totalOut
    };
    hipError_t e = hipLaunchCooperativeKernel(
        (const void*)coop_kernel, dim3(blocks), dim3(256), args, 0, stream);
    if (e == hipSuccess) return;

    // ---- Fallback: proven round-12 path ----
    (void)hipMemsetAsync(d_out, 0, (chunk0 + L) * sizeof(float), stream);
    count_kernel<<<blocks, 256, 0, stream>>>(
        xyz, new_xyz, rois, counts, N, Nb, M, K, nsample);
    scan_kernel<<<1, 1024, 0, stream>>>(counts, offsets, N);
    emit_kernel<<<blocks, 256, 0, stream>>>(
        xyz, new_xyz, rois, features, offsets, out_feat, out_idx,
        N, Nb, M, K, C, nsample);
}

// Round 14
// 91.169 us; speedup vs baseline: 3.4872x; 3.4872x over previous
//
#include <hip/hip_runtime.h>

// QueryAndGroup — test dims B=2, Nb=512, N=1024, M=64, K=216, C=32, ns=32.
// Inputs f32; OUTPUT f32: [group_features (L,3+C) | set_new_indices (L,)].
// Round-13 post-mortem: cooperative fusion REGRESSED (318 us; coop kernel 243
// us alone) — grid.sync() on 8-XCD MI355X costs ~100 us each (device-scope
// barrier + cross-XCD L2 coherence). Reverted to stream-ordered dispatches.
// Round-14: 3 dispatches. count kernel also zeroes the output (memset dispatch
// folded in) and records matched j's to ws; emit is a pure gather with
// contiguous coalesced writes. Non-kernel harness overhead measured ~75 us
// (poison fills + restore); my pipeline target <20 us.

#pragma clang fp contract(off)

typedef unsigned long long u64;

#define MAXN 4096

// ---- count: wave per row; zero-output slice; x4-batched test; record j's ----
__global__ __launch_bounds__(256) void count_kernel(
    const float* __restrict__ xyz, const float* __restrict__ new_xyz,
    const float* __restrict__ rois, int* __restrict__ counts,
    int* __restrict__ ballidx, float* __restrict__ out_all,
    int N, int Nb, int M, int K, int nsample, int totalOut)
{
    __shared__ int plist[4][64];
    const int wave = threadIdx.x >> 6;
    const int lane = threadIdx.x & 63;
    const int r = blockIdx.x * 4 + wave;
    const u64 laneLt = (1ull << lane) - 1ull;

    // Zero this block's slice of the output (folded memset; emit runs later
    // in stream order, so no race).
    {
        const int gtid = blockIdx.x * 256 + threadIdx.x;
        const int gthreads = gridDim.x * 256;
        for (int i = gtid; i < totalOut; i += gthreads) out_all[i] = 0.0f;
    }

    if (r >= N) return;

    const int b  = r / Nb;
    const float px = xyz[3 * r + 0];
    const float py = xyz[3 * r + 1];
    const float pz = xyz[3 * r + 2];

    bool pass = false;
    if (lane < M) {
        const float* rp = rois + (size_t)(b * M + lane) * 7;
        const float dx = rp[3], dy = rp[4], dz = rp[5];
        const float r2 = (dx * dx + dy * dy) + dz * dz;   // numpy association
        const float ex = px - rp[0], ey = py - rp[1], ez = pz - rp[2];
        pass = ((ex * ex + ey * ey) + ez * ez) <= r2;
    }
    const u64 roiMask = __ballot(pass);
    if (!roiMask) { if (lane == 0) counts[r] = 0; return; }
    if (pass) plist[wave][__popcll(roiMask & laneLt)] = lane;  // ascending m

    const int P = __popcll(roiMask);
    const int total = P * K;
    const float* nb_ = new_xyz + (size_t)(b * M * K) * 3;
    int* bi = ballidx + (size_t)r * nsample;

    int cnt = 0;
    for (int base = 0; base < total && cnt < nsample; base += 256) {
        bool match[4];
        int jj[4];
        #pragma unroll
        for (int u = 0; u < 4; u++) {          // issue all loads before ballots
            const int p = base + u * 64 + lane;
            match[u] = false; jj[u] = 0;
            if (p < total) {
                const int ri = p / K;
                const int k  = p - ri * K;
                const int j  = plist[wave][ri] * K + k;
                jj[u] = j;
                const float* gp = nb_ + (size_t)j * 3;
                const float ax = px - gp[0], ay = py - gp[1], az = pz - gp[2];
                match[u] = ((ax * ax + ay * ay) + az * az) <= 1.0f;
            }
        }
        #pragma unroll
        for (int u = 0; u < 4; u++) {
            const u64 mm = __ballot(match[u]);
            const int slot = cnt + __popcll(mm & laneLt);
            if (match[u] && slot < nsample) bi[slot] = jj[u];
            cnt += __popcll(mm);
        }
    }
    if (lane == 0) counts[r] = cnt > nsample ? nsample : cnt;
}

// ---- scan: exclusive scan of counts[N], N <= 4096, one block ----
__global__ __launch_bounds__(1024) void scan_kernel(
    const int* __restrict__ counts, int* __restrict__ offsets, int N)
{
    __shared__ int waveAux[16];
    const int t = threadIdx.x;
    const int lane = t & 63;
    const int wid = t >> 6;
    const int base = t * 4;
    int c[4];
    int s = 0;
    #pragma unroll
    for (int i = 0; i < 4; i++) {
        c[i] = (base + i < N) ? counts[base + i] : 0;
        s += c[i];
    }
    int incl = s;
    #pragma unroll
    for (int d = 1; d < 64; d <<= 1) {
        int v = __shfl_up(incl, d, 64);
        if (lane >= d) incl += v;
    }
    if (lane == 63) waveAux[wid] = incl;
    __syncthreads();
    if (t < 16) {
        int v = waveAux[t];
        #pragma unroll
        for (int d = 1; d < 16; d <<= 1) {
            int u = __shfl_up(v, d, 64);
            if (t >= d) v += u;
        }
        waveAux[t] = v;
    }
    __syncthreads();
    int run = (wid ? waveAux[wid - 1] : 0) + incl - s;
    #pragma unroll
    for (int i = 0; i < 4; i++) {
        if (base + i < N) offsets[base + i] = run;
        run += c[i];
    }
}

// ---- emit: wave per row; pure gather from ballidx; coalesced writes ----
__global__ __launch_bounds__(256) void emit_kernel(
    const float* __restrict__ xyz, const float* __restrict__ new_xyz,
    const float* __restrict__ features,
    const int* __restrict__ counts, const int* __restrict__ offsets,
    const int* __restrict__ ballidx,
    float* __restrict__ out_feat, float* __restrict__ out_idx,
    int N, int Nb, int M, int K, int C, int nsample)
{
    const int wave = threadIdx.x >> 6;
    const int lane = threadIdx.x & 63;
    const int r = blockIdx.x * 4 + wave;
    if (r >= N) return;

    const int cnt = counts[r];
    if (cnt <= 0) return;

    const int b  = r / Nb;
    const int MK = M * K;
    const int obase = offsets[r];
    const int* bi = ballidx + (size_t)r * nsample;
    const float px = xyz[3 * r + 0];
    const float py = xyz[3 * r + 1];
    const float pz = xyz[3 * r + 2];
    const float* fr = features + (size_t)r * C;
    const float* nb_ = new_xyz + (size_t)b * MK * 3;
    const int W = 3 + C;

    // Feature block: cnt*W contiguous floats at out_feat + obase*W.
    float* dst = out_feat + (size_t)obase * W;
    const int tot = cnt * W;
    for (int idx = lane; idx < tot; idx += 64) {
        const int s = idx / W;
        const int c = idx - s * W;
        const int j = bi[s];
        float v;
        if (c == 0)      v = px - nb_[(size_t)j * 3 + 0];
        else if (c == 1) v = py - nb_[(size_t)j * 3 + 1];
        else if (c == 2) v = pz - nb_[(size_t)j * 3 + 2];
        else             v = fr[c - 3];
        dst[idx] = v;
    }
    for (int s = lane; s < cnt; s += 64)
        out_idx[obase + s] = (float)(b * MK + bi[s]);
}

extern "C" void kernel_launch(void* const* d_in, const int* in_sizes, int n_in,
                              void* d_out, int out_size, void* d_ws, size_t ws_size,
                              hipStream_t stream) {
    if (n_in < 5) return;

    // ---- Role assignment by SIZE (unique on the true test sizes). ----
    int bc = 0;
    for (int i = 1; i < n_in; i++) if (in_sizes[i] < in_sizes[bc]) bc = i;
    const int B = in_sizes[bc];
    if (B < 1) return;

    int xi = -1, nwi = -1, ri = -1, fi = -1;
    int N = 0, M = 0, K = 0, C = 0, nsample = 0;

    for (int rr = 0; rr < n_in && xi < 0; rr++) {
        if (rr == bc) continue;
        if (in_sizes[rr] % (7 * B)) continue;            // rois = B*M*7
        const int M_ = in_sizes[rr] / (7 * B);
        if (M_ < 1 || M_ > 64) continue;
        for (int xx = 0; xx < n_in && xi < 0; xx++) {
            if (xx == bc || xx == rr) continue;
            if (in_sizes[xx] % 3) continue;              // xyz = N*3
            const int N_ = in_sizes[xx] / 3;
            if (N_ < B || N_ % B || N_ > MAXN) continue;
            for (int nn = 0; nn < n_in && xi < 0; nn++) {
                if (nn == bc || nn == rr || nn == xx) continue;
                if (in_sizes[nn] % (3 * B * M_)) continue;   // new_xyz = B*M*K*3
                const int K_ = in_sizes[nn] / (3 * B * M_);
                if (K_ < 1) continue;
                for (int ff = 0; ff < n_in && xi < 0; ff++) {
                    if (ff == bc || ff == rr || ff == xx || ff == nn) continue;
                    if (in_sizes[ff] % N_) continue;         // features = N*C
                    const int C_ = in_sizes[ff] / N_;
                    if (C_ < 1) continue;
                    if (out_size % (4 + C_)) continue;       // out = L*(4+C) f32
                    const long long L_ = (long long)out_size / (4 + C_);
                    if (L_ % N_) continue;
                    const int ns = (int)(L_ / N_);
                    if (ns < 1 || ns > 1024) continue;
                    xi = xx; nwi = nn; ri = rr; fi = ff;
                    N = N_; M = M_; K = K_; C = C_; nsample = ns;
                }
            }
        }
    }
    if (xi < 0) return;

    const float* xyz      = (const float*)d_in[xi];
    const float* new_xyz  = (const float*)d_in[nwi];
    const float* rois     = (const float*)d_in[ri];
    const float* features = (const float*)d_in[fi];
    const int Nb = N / B;

    const size_t L      = (size_t)N * nsample;
    const size_t chunk0 = L * (size_t)(3 + C);
    const int totalOut  = (int)(chunk0 + L);

    float* out_feat = (float*)d_out;
    float* out_idx  = out_feat + chunk0;

    // ws: counts[N] + offsets[N] + ballidx[N*ns]
    const size_t wsNeed = ((size_t)2 * N + (size_t)N * nsample) * sizeof(int);
    if (ws_size < wsNeed) return;
    int* counts  = (int*)d_ws;
    int* offsets = counts + N;
    int* ballidx = offsets + N;

    const int blocks = (N + 3) / 4;   // one wave per row

    count_kernel<<<blocks, 256, 0, stream>>>(
        xyz, new_xyz, rois, counts, ballidx, out_feat,
        N, Nb, M, K, nsample, totalOut);
    scan_kernel<<<1, 1024, 0, stream>>>(counts, offsets, N);
    emit_kernel<<<blocks, 256, 0, stream>>>(
        xyz, new_xyz, features, counts, offsets, ballidx,
        out_feat, out_idx, N, Nb, M, K, C, nsample);
}